// Round 2
// baseline (8825.868 us; speedup 1.0000x reference)
//
#include <hip/hip_runtime.h>

#define TT 512
#define HH 1024
#define NC 8192   // 2 dirs * 4 gates * 1024 units
#define LSTRIDE 32  // floats per h-line (128B): [0:16) h, [16] flag, rest pad

// ---- ws layout (float units) ----
// [0, 4194304)          Gx[512][8192]
// [4194304, ...)        OVERLAID: emb[512][1024] (phase 1 only)
//                       then lines[513][2][64][LSTRIDE] (phase 2 only)
#define WS_GX    0
#define WS_EMB   4194304
#define WS_LINES 4194304

__device__ __forceinline__ float rdlane(float v, int l) {
  return __int_as_float(__builtin_amdgcn_readlane(__float_as_int(v), l));
}
__device__ __forceinline__ float fsig(float x) {
  float e = __builtin_amdgcn_exp2f(-1.44269504f * x);
  return __builtin_amdgcn_rcpf(1.f + e);
}
__device__ __forceinline__ float ftanh(float x) {
  float e = __builtin_amdgcn_exp2f(2.88539009f * x);
  return fmaf(-2.f, __builtin_amdgcn_rcpf(1.f + e), 1.f);
}

// ---------------- Phase 1a: embedding gather ----------------
__global__ __launch_bounds__(256) void k_embed(const int* __restrict__ tok,
                                               const float* __restrict__ E,
                                               const float* __restrict__ be,
                                               float* __restrict__ emb) {
  int i = blockIdx.x * 256 + threadIdx.x;
  int t = i >> 10, h = i & (HH - 1);
  emb[i] = E[(size_t)tok[t] * HH + h] + be[h];
}

// ---------------- Phase 1b: input projection GEMM ----------------
// Gx[t][c] = sum_i emb[t][i] * W_d[g][i][u] + b_d[g][u]
// c = d*4096 + bp*64 + l,  u = bp*16 + (l>>2), g = l&3   (scan-lane order)
__global__ __launch_bounds__(256) void k_gemm(const float* __restrict__ emb,
                                              const float* __restrict__ Wr,
                                              const float* __restrict__ Wl,
                                              const float* __restrict__ br,
                                              const float* __restrict__ bl,
                                              float* __restrict__ Gx) {
  __shared__ float As[32][132];
  __shared__ float Bs[32][68];
  int ct = blockIdx.x, ttile = blockIdx.y;
  int tid = threadIdx.x;
  int d = ct >> 6;
  int bp = ct & 63;
  int u0 = bp << 4;
  const float* W = d ? Wl : Wr;
  const float* bias = d ? bl : br;
  int t0 = ttile * 128;
  int tc = tid & 15, tr = tid >> 4;

  float acc[8][4];
#pragma unroll
  for (int i = 0; i < 8; ++i)
#pragma unroll
    for (int j = 0; j < 4; ++j) acc[i][j] = 0.f;

  int sk = tid & 31, st = tid >> 5;
  int sc = tid & 63, skb = tid >> 6;
  int sg = sc & 3, su = u0 + (sc >> 2);

  for (int k0 = 0; k0 < HH; k0 += 32) {
    __syncthreads();
#pragma unroll
    for (int pass = 0; pass < 16; ++pass) {
      int t = st + (pass << 3);
      As[sk][t] = emb[(size_t)(t0 + t) * HH + k0 + sk];
    }
#pragma unroll
    for (int pass = 0; pass < 8; ++pass) {
      int k = skb + (pass << 2);
      Bs[k][sc] = W[((size_t)sg * 2048 + k0 + k) * HH + su];
    }
    __syncthreads();
#pragma unroll
    for (int k = 0; k < 32; ++k) {
      float4 bv = *(const float4*)&Bs[k][tc << 2];
      float4 a0 = *(const float4*)&As[k][tr << 3];
      float4 a1 = *(const float4*)&As[k][(tr << 3) + 4];
      float av[8] = {a0.x, a0.y, a0.z, a0.w, a1.x, a1.y, a1.z, a1.w};
#pragma unroll
      for (int i = 0; i < 8; ++i) {
        acc[i][0] = fmaf(av[i], bv.x, acc[i][0]);
        acc[i][1] = fmaf(av[i], bv.y, acc[i][1]);
        acc[i][2] = fmaf(av[i], bv.z, acc[i][2]);
        acc[i][3] = fmaf(av[i], bv.w, acc[i][3]);
      }
    }
  }
  int c0 = ct << 6;
  float b0 = bias[0 * HH + u0 + tc];
  float b1 = bias[1 * HH + u0 + tc];
  float b2 = bias[2 * HH + u0 + tc];
  float b3 = bias[3 * HH + u0 + tc];
#pragma unroll
  for (int i = 0; i < 8; ++i) {
    int t = t0 + (tr << 3) + i;
    float4 o;
    o.x = acc[i][0] + b0;
    o.y = acc[i][1] + b1;
    o.z = acc[i][2] + b2;
    o.w = acc[i][3] + b3;
    *(float4*)&Gx[(size_t)t * NC + c0 + (tc << 2)] = o;
  }
}

// ---------------- Phase 2: persistent bidirectional LSTM scan ----------------
// 128 blocks (64 fwd, 64 bwd) x 1024 threads (16 waves). Block owns 16 hidden
// units (64 gate-outputs = lane dim). Wave w owns h-slice [64w, 64w+64).
// Recurrent weights in registers. Cross-block h exchange via write-once
// per-step lines: {16 h floats, seq flag} per producer block; consumers poll
// only their own 4 producers' flags (distributed, no atomic RMW contention).
__global__ __launch_bounds__(1024, 1) void k_scan(const float* __restrict__ Wr,
                                                  const float* __restrict__ Wl,
                                                  const float* __restrict__ Gx,
                                                  float* __restrict__ lines,
                                                  float* __restrict__ out) {
  int b = blockIdx.x;
  int d = b >> 6, bp = b & 63;
  int tid = threadIdx.x;
  int w = tid >> 6, l = tid & 63;
  int u0 = bp << 4;
  int g = l & 3, ur = l >> 2;
  const float* W = d ? Wl : Wr;

  // one-time register load of recurrent weights: W_d[g][1024 + i][u]
  float wreg[64];
  {
    const float* wb = W + ((size_t)g * 2048 + HH + (w << 6)) * HH + (u0 + ur);
#pragma unroll
    for (int j = 0; j < 64; ++j) wreg[j] = wb[(size_t)j * HH];
  }

  __shared__ float red[16][64];
  float c_reg = 0.f;
  const float* gxbase = Gx + (d << 12) + (bp << 6);

  for (int t = 0; t < TT; ++t) {
    // independent of h: issue Gx load early (completes during poll)
    float s_gx = 0.f;
    if (w == 0) {
      int rt = d ? (TT - 1 - t) : t;  // backward consumes reversed sequence
      s_gx = gxbase[(size_t)rt * NC + l];
    }

    float partial = 0.f;
    if (t > 0) {
      size_t lbase = (size_t)(((t << 1) + d) << 6) * LSTRIDE;
      const int* fp =
          (const int*)&lines[lbase + (size_t)((w << 2) + (l & 3)) * LSTRIDE + 16];
      while (true) {
        int f = __hip_atomic_load(fp, __ATOMIC_RELAXED, __HIP_MEMORY_SCOPE_AGENT);
        if (__all(f == t)) break;
      }
      __builtin_amdgcn_fence(__ATOMIC_ACQUIRE, "agent");
      float hv = lines[lbase + (size_t)((w << 2) + (l >> 4)) * LSTRIDE + (l & 15)];
      float acc0 = 0.f, acc1 = 0.f;
#pragma unroll
      for (int j = 0; j < 64; j += 2) {
        acc0 = fmaf(rdlane(hv, j), wreg[j], acc0);
        acc1 = fmaf(rdlane(hv, j + 1), wreg[j + 1], acc1);
      }
      partial = acc0 + acc1;
    }
    red[w][l] = partial;
    __syncthreads();

    float sval = 0.f;
    if (w == 0) {
      sval = s_gx;
#pragma unroll
      for (int ww = 0; ww < 16; ++ww) sval += red[ww][l];
    }
    __syncthreads();  // red[] reusable next iteration

    if (w == 0) {
      int lb = l & ~3;
      float gi = __shfl(sval, lb + 0);
      float go = __shfl(sval, lb + 1);
      float gf = __shfl(sval, lb + 2);
      float gc = __shfl(sval, lb + 3);
      float ig = fsig(gi);
      float og = fsig(go);
      float fg = fsig(gf);
      float cg = ftanh(gc);
      c_reg = fg * c_reg + ig * cg;
      float hval = og * ftanh(c_reg);

      size_t nbase =
          (size_t)((((t + 1) << 1) + d) << 6) * LSTRIDE + (size_t)bp * LSTRIDE;
      if (g == 0) lines[nbase + ur] = hval;  // 16 h floats, one 64B segment
      __builtin_amdgcn_fence(__ATOMIC_RELEASE, "agent");
      if (l == 0) {
        __hip_atomic_store((int*)&lines[nbase + 16], t + 1, __ATOMIC_RELAXED,
                           __HIP_MEMORY_SCOPE_AGENT);
      }
      // fire-and-forget outputs (after flag: not on the critical chain)
      if (g == 0) {
        int uu = u0 + ur;
        out[(size_t)t * 2048 + (d << 10) + uu] = hval;  // annotations
        if (d == 0 && t == TT - 1) {
          out[(size_t)TT * 2048 + uu] = hval;       // h_f
          out[(size_t)TT * 2048 + HH + uu] = c_reg; // c_f
        }
      }
    }
  }
}

extern "C" void kernel_launch(void* const* d_in, const int* in_sizes, int n_in,
                              void* d_out, int out_size, void* d_ws, size_t ws_size,
                              hipStream_t stream) {
  const int* tok = (const int*)d_in[0];
  const float* E = (const float*)d_in[1];
  const float* be = (const float*)d_in[2];
  const float* Wr = (const float*)d_in[3];
  const float* br = (const float*)d_in[4];
  const float* Wl = (const float*)d_in[5];
  const float* bl = (const float*)d_in[6];
  float* out = (float*)d_out;
  float* ws = (float*)d_ws;

  float* Gx = ws + WS_GX;
  float* emb = ws + WS_EMB;    // phase-1 lifetime only
  float* lines = ws + WS_LINES;  // phase-2 lifetime (overlays emb)

  // No memset needed: flags are write-once per-step slots; 0xAA poison can
  // never equal a valid flag value t in [1,512], and slot 0 is never read.

  k_embed<<<dim3(TT * HH / 256), dim3(256), 0, stream>>>(tok, E, be, emb);
  k_gemm<<<dim3(128, 4), dim3(256), 0, stream>>>(emb, Wr, Wl, br, bl, Gx);
  k_scan<<<dim3(128), dim3(1024), 0, stream>>>(Wr, Wl, Gx, lines, out);
}

// Round 3
// 1276.698 us; speedup vs baseline: 6.9130x; 6.9130x over previous
//
#include <hip/hip_runtime.h>

#define TT 512
#define HH 1024
#define NC 8192     // 2 dirs * 4 gates * 1024 units
#define TAGBASE 0x40000000u  // tag floats ~2.0; can never alias emb/h/poison data

// ---- ws layout (float units) ----
// [0, 4194304)            Gx[512][8192]
// [4194304, 4718592)      emb[512][1024]           (phase 1 only)
// [4194304, 6291456)      xch[512][2][1024] uint64 (phase 2 only, overlays emb;
//                          stale emb floats ~N(0,4e-4) can't equal tag 2.0+eps)
#define WS_GX    0
#define WS_EMB   4194304
#define WS_X     4194304

__device__ __forceinline__ float rdlane(float v, int l) {
  return __int_as_float(__builtin_amdgcn_readlane(__float_as_int(v), l));
}
__device__ __forceinline__ float fsig(float x) {
  float e = __builtin_amdgcn_exp2f(-1.44269504f * x);
  return __builtin_amdgcn_rcpf(1.f + e);
}
__device__ __forceinline__ float ftanh(float x) {
  float e = __builtin_amdgcn_exp2f(2.88539009f * x);
  return fmaf(-2.f, __builtin_amdgcn_rcpf(1.f + e), 1.f);
}

// ---------------- Phase 1a: embedding gather ----------------
__global__ __launch_bounds__(256) void k_embed(const int* __restrict__ tok,
                                               const float* __restrict__ E,
                                               const float* __restrict__ be,
                                               float* __restrict__ emb) {
  int i = blockIdx.x * 256 + threadIdx.x;
  int t = i >> 10, h = i & (HH - 1);
  emb[i] = E[(size_t)tok[t] * HH + h] + be[h];
}

// ---------------- Phase 1b: input projection GEMM ----------------
// Gx[t][c] = sum_i emb[t][i] * W_d[g][i][u] + b_d[g][u]
// c = d*4096 + bp*64 + l,  u = bp*16 + (l>>2), g = l&3   (scan-lane order)
__global__ __launch_bounds__(256) void k_gemm(const float* __restrict__ emb,
                                              const float* __restrict__ Wr,
                                              const float* __restrict__ Wl,
                                              const float* __restrict__ br,
                                              const float* __restrict__ bl,
                                              float* __restrict__ Gx) {
  __shared__ float As[32][132];
  __shared__ float Bs[32][68];
  int ct = blockIdx.x, ttile = blockIdx.y;
  int tid = threadIdx.x;
  int d = ct >> 6;
  int bp = ct & 63;
  int u0 = bp << 4;
  const float* W = d ? Wl : Wr;
  const float* bias = d ? bl : br;
  int t0 = ttile * 128;
  int tc = tid & 15, tr = tid >> 4;

  float acc[8][4];
#pragma unroll
  for (int i = 0; i < 8; ++i)
#pragma unroll
    for (int j = 0; j < 4; ++j) acc[i][j] = 0.f;

  int sk = tid & 31, st = tid >> 5;
  int sc = tid & 63, skb = tid >> 6;
  int sg = sc & 3, su = u0 + (sc >> 2);

  for (int k0 = 0; k0 < HH; k0 += 32) {
    __syncthreads();
#pragma unroll
    for (int pass = 0; pass < 16; ++pass) {
      int t = st + (pass << 3);
      As[sk][t] = emb[(size_t)(t0 + t) * HH + k0 + sk];
    }
#pragma unroll
    for (int pass = 0; pass < 8; ++pass) {
      int k = skb + (pass << 2);
      Bs[k][sc] = W[((size_t)sg * 2048 + k0 + k) * HH + su];
    }
    __syncthreads();
#pragma unroll
    for (int k = 0; k < 32; ++k) {
      float4 bv = *(const float4*)&Bs[k][tc << 2];
      float4 a0 = *(const float4*)&As[k][tr << 3];
      float4 a1 = *(const float4*)&As[k][(tr << 3) + 4];
      float av[8] = {a0.x, a0.y, a0.z, a0.w, a1.x, a1.y, a1.z, a1.w};
#pragma unroll
      for (int i = 0; i < 8; ++i) {
        acc[i][0] = fmaf(av[i], bv.x, acc[i][0]);
        acc[i][1] = fmaf(av[i], bv.y, acc[i][1]);
        acc[i][2] = fmaf(av[i], bv.z, acc[i][2]);
        acc[i][3] = fmaf(av[i], bv.w, acc[i][3]);
      }
    }
  }
  int c0 = ct << 6;
  float b0 = bias[0 * HH + u0 + tc];
  float b1 = bias[1 * HH + u0 + tc];
  float b2 = bias[2 * HH + u0 + tc];
  float b3 = bias[3 * HH + u0 + tc];
#pragma unroll
  for (int i = 0; i < 8; ++i) {
    int t = t0 + (tr << 3) + i;
    float4 o;
    o.x = acc[i][0] + b0;
    o.y = acc[i][1] + b1;
    o.z = acc[i][2] + b2;
    o.w = acc[i][3] + b3;
    *(float4*)&Gx[(size_t)t * NC + c0 + (tc << 2)] = o;
  }
}

// ---------------- Phase 2: persistent bidirectional LSTM scan ----------------
// 128 blocks (64 fwd, 64 bwd) x 1024 threads (16 waves). Block owns 16 hidden
// units (64 gate-outputs = lane dim); wave w consumes h-slice [64w, 64w+64).
// Recurrent weights in registers. h exchange: write-once per-step slots of
// self-validating 8B words {tag|float}: relaxed agent atomics, NO fences, no
// separate flag, no acquire invalidations. Poll load == data load.
__global__ __launch_bounds__(1024, 1) void k_scan(const float* __restrict__ Wr,
                                                  const float* __restrict__ Wl,
                                                  const float* __restrict__ Gx,
                                                  unsigned long long* __restrict__ xch,
                                                  float* __restrict__ out) {
  int b = blockIdx.x;
  int d = b >> 6, bp = b & 63;
  int tid = threadIdx.x;
  int w = tid >> 6, l = tid & 63;
  int u0 = bp << 4;
  int g = l & 3, ur = l >> 2;
  const float* W = d ? Wl : Wr;

  // one-time register load of recurrent weights: W_d[g][1024 + i][u]
  float wreg[64];
  {
    const float* wb = W + ((size_t)g * 2048 + HH + (w << 6)) * HH + (u0 + ur);
#pragma unroll
    for (int j = 0; j < 64; ++j) wreg[j] = wb[(size_t)j * HH];
  }

  __shared__ float red[2][16][64];
  float c_reg = 0.f;
  const float* gxbase = Gx + (d << 12) + (bp << 6);
  // slot s (s=1..512) lives at xch[(s-1)*2048 + d*1024 + unit]
  unsigned long long* xd = xch + ((size_t)d << 10);

  for (int t = 0; t < TT; ++t) {
    int p = t & 1;
    // independent of h: issue Gx load early (completes during poll)
    float s_gx = 0.f;
    if (w == 0) {
      int rt = d ? (TT - 1 - t) : t;  // backward consumes reversed sequence
      s_gx = gxbase[(size_t)rt * NC + l];
    }

    float partial = 0.f;
    if (t > 0) {
      unsigned long long* slot = xd + (((size_t)(t - 1)) << 11) + (w << 6) + l;
      unsigned int want = TAGBASE + (unsigned int)t;
      unsigned long long v;
      while (true) {
        v = __hip_atomic_load(slot, __ATOMIC_RELAXED, __HIP_MEMORY_SCOPE_AGENT);
        if (__all((unsigned int)(v >> 32) == want)) break;
        __builtin_amdgcn_s_sleep(1);
      }
      float hv = __int_as_float((int)(unsigned int)v);  // h[64w + l], in-register
      float acc0 = 0.f, acc1 = 0.f;
#pragma unroll
      for (int j = 0; j < 64; j += 2) {
        acc0 = fmaf(rdlane(hv, j), wreg[j], acc0);
        acc1 = fmaf(rdlane(hv, j + 1), wreg[j + 1], acc1);
      }
      partial = acc0 + acc1;
    }
    red[p][w][l] = partial;
    __syncthreads();  // single barrier/step (red is double-buffered)

    if (w == 0) {
      float sval = s_gx;
#pragma unroll
      for (int ww = 0; ww < 16; ++ww) sval += red[p][ww][l];
      int lb = l & ~3;
      float gi = __shfl(sval, lb + 0);
      float go = __shfl(sval, lb + 1);
      float gf = __shfl(sval, lb + 2);
      float gc = __shfl(sval, lb + 3);
      float ig = fsig(gi);
      float og = fsig(go);
      float fg = fsig(gf);
      float cg = ftanh(gc);
      c_reg = fg * c_reg + ig * cg;
      float hval = og * ftanh(c_reg);

      if (g == 0) {
        int uu = u0 + ur;
        // publish h_{t+1}: single 8B tagged store, fire-and-forget
        unsigned long long val =
            (((unsigned long long)(TAGBASE + (unsigned int)(t + 1))) << 32) |
            (unsigned int)__float_as_int(hval);
        __hip_atomic_store(xd + (((size_t)t) << 11) + uu, val, __ATOMIC_RELAXED,
                           __HIP_MEMORY_SCOPE_AGENT);
        // fire-and-forget outputs (off the critical chain)
        out[(size_t)t * 2048 + (d << 10) + uu] = hval;  // annotations
        if (d == 0 && t == TT - 1) {
          out[(size_t)TT * 2048 + uu] = hval;        // h_f
          out[(size_t)TT * 2048 + HH + uu] = c_reg;  // c_f
        }
      }
    }
  }
}

extern "C" void kernel_launch(void* const* d_in, const int* in_sizes, int n_in,
                              void* d_out, int out_size, void* d_ws, size_t ws_size,
                              hipStream_t stream) {
  const int* tok = (const int*)d_in[0];
  const float* E = (const float*)d_in[1];
  const float* be = (const float*)d_in[2];
  const float* Wr = (const float*)d_in[3];
  const float* br = (const float*)d_in[4];
  const float* Wl = (const float*)d_in[5];
  const float* bl = (const float*)d_in[6];
  float* out = (float*)d_out;
  float* ws = (float*)d_ws;

  float* Gx = ws + WS_GX;
  float* emb = ws + WS_EMB;                              // phase-1 lifetime
  unsigned long long* xch = (unsigned long long*)(ws + WS_X);  // phase-2 lifetime

  // No memset: exchange slots are write-once; tag TAGBASE+t (float ~2.0) can't
  // alias 0xAA poison, stale emb values (~N(0,4e-4)), or any h value.

  k_embed<<<dim3(TT * HH / 256), dim3(256), 0, stream>>>(tok, E, be, emb);
  k_gemm<<<dim3(128, 4), dim3(256), 0, stream>>>(emb, Wr, Wl, br, bl, Gx);
  k_scan<<<dim3(128), dim3(1024), 0, stream>>>(Wr, Wl, Gx, xch, out);
}